// Round 1
// 333.257 us; speedup vs baseline: 1.0671x; 1.0671x over previous
//
#include <hip/hip_runtime.h>
#include <stdint.h>

// Problem constants (fixed by the reference)
#define N_TOK 8192
#define IN_F 4096
#define OUT_F 4096
#define BS 256
#define ABPI 5
#define NFLAT 80          // 16 output blocks x 5 slots = all (g,a) pairs

typedef __attribute__((ext_vector_type(8))) short short8;    // 8 bf16 = 4 VGPRs (MFMA A/B frag)
typedef __attribute__((ext_vector_type(4))) float floatx4;   // MFMA C/D frag
typedef __attribute__((ext_vector_type(4))) unsigned short ushort4v;
typedef __attribute__((ext_vector_type(8))) unsigned short ushort8v;

__device__ __forceinline__ unsigned short f2bf(float f) {
  union { float f; unsigned int u; } v; v.f = f;
  unsigned int r = v.u + 0x7FFFu + ((v.u >> 16) & 1u);   // RNE
  return (unsigned short)(r >> 16);
}

__device__ __forceinline__ void async16(const void* g, void* l) {
  // per-lane global addr; LDS dst = wave-uniform base + lane*16 (our mapping is tid-contiguous)
  __builtin_amdgcn_global_load_lds((const __attribute__((address_space(1))) void*)g,
                                   (__attribute__((address_space(3))) void*)l, 16, 0, 0);
}

// ---------------- kernel 1: x fp32 -> bf16 ----------------
__global__ void cvt_x_kernel(const float4* __restrict__ x, ushort8v* __restrict__ xb) {
  int idx = blockIdx.x * 256 + threadIdx.x;   // one ushort8 (8 elems) per thread
  float4 a = x[idx * 2], b = x[idx * 2 + 1];
  ushort8v o;
  o[0] = f2bf(a.x); o[1] = f2bf(a.y); o[2] = f2bf(a.z); o[3] = f2bf(a.w);
  o[4] = f2bf(b.x); o[5] = f2bf(b.y); o[6] = f2bf(b.z); o[7] = f2bf(b.w);
  xb[idx] = o;
}

// ---------------- kernel 2: weight fp32 -> bf16, transposed per (g,a) block ----
// weight[(g*256+k)*1280 + a*256 + o]  ->  wt[(g*5+a)*65536 + o*256 + k]
__global__ void cvt_w_kernel(const float* __restrict__ w, unsigned short* __restrict__ wt) {
  __shared__ unsigned short tile[64][68];   // [o][k], padded
  int b = blockIdx.x;                 // 80 * 16
  int fi = b >> 4;
  int t  = b & 15;
  int k0 = (t >> 2) * 64, o0 = (t & 3) * 64;
  int g = fi / ABPI, a = fi % ABPI;
  int tid = threadIdx.x;
  int tr = tid >> 4, tc = tid & 15;   // 16 float4 per 64-wide row
  #pragma unroll
  for (int i = 0; i < 4; ++i) {
    int k = k0 + i * 16 + tr;
    const float* src = w + (size_t)(g * 256 + k) * (ABPI * BS) + a * BS + o0 + tc * 4;
    float4 v = *(const float4*)src;
    tile[tc * 4 + 0][i * 16 + tr] = f2bf(v.x);
    tile[tc * 4 + 1][i * 16 + tr] = f2bf(v.y);
    tile[tc * 4 + 2][i * 16 + tr] = f2bf(v.z);
    tile[tc * 4 + 3][i * 16 + tr] = f2bf(v.w);
  }
  __syncthreads();
  #pragma unroll
  for (int i = 0; i < 4; ++i) {
    int o = i * 16 + tr;
    unsigned short* dst = wt + (size_t)fi * (BS * BS) + (size_t)(o0 + o) * BS + k0 + tc * 4;
    *(ushort4v*)dst = *(const ushort4v*)&tile[o][tc * 4];
  }
}

// ---------------- kernel 3: butterfly block-sparse GEMM, deep-pipelined -------
// 256x128 tile, 8 waves (2M x 4N), BK=64, TRIPLE-buffered LDS.
// While computing K-tile t (buf t%3) we stage K-tile t+2 (buf (t+2)%3, which
// holds tile t-1 -> dead: its reads were lgkmcnt(0)-drained >=1 barrier ago).
// One counted s_waitcnt vmcnt(6) per K-tile boundary leaves exactly tile t+2's
// 6 loads in flight and forces tile t+1 complete. Loads never drain to 0 in loop.

#define BM 256
#define BN 128
#define BK 64
#define ABYTES 32768              // BM*BK*2
#define BBYTES 16384              // BN*BK*2
#define BUFBYTES 49152            // A + B per K-tile
#define SMEM_TOTAL 147456         // 3 buffers

__device__ __forceinline__ void ld_frags(const char* Ab, const char* Bb,
                                         int rA, int rB, int c0, int c1, int mbyte, bool rdB,
                                         short8 (&af)[4][2], short8 (&bfr)[2][2]) {
  #pragma unroll
  for (int m = 0; m < 4; ++m) {
    const char* p = Ab + rA + mbyte + m * 2048;
    af[m][0] = *(const short8*)(p + c0);
    af[m][1] = *(const short8*)(p + c1);
  }
  if (rdB) {
    #pragma unroll
    for (int n = 0; n < 2; ++n) {
      const char* p = Bb + rB + n * 2048;
      bfr[n][0] = *(const short8*)(p + c0);
      bfr[n][1] = *(const short8*)(p + c1);
    }
  }
}

__device__ __forceinline__ void mma_frags(int mbase, const short8 (&af)[4][2],
                                          const short8 (&bfr)[2][2], floatx4 (&acc)[8][2]) {
  #pragma unroll
  for (int m = 0; m < 4; ++m)
    #pragma unroll
    for (int n = 0; n < 2; ++n) {
      acc[mbase + m][n] = __builtin_amdgcn_mfma_f32_16x16x32_bf16(af[m][0], bfr[n][0], acc[mbase + m][n], 0, 0, 0);
      acc[mbase + m][n] = __builtin_amdgcn_mfma_f32_16x16x32_bf16(af[m][1], bfr[n][1], acc[mbase + m][n], 0, 0, 0);
    }
}

// 2 A-issues + 1 B-issue per phase (ph0: A rows [0,128), B rows [0,64))
#define STAGE_PH0(uA, uB, Adst, Bdst)              \
  do {                                             \
    async16(pA0 + (uA), (Adst)         + tid16);   \
    async16(pA1 + (uA), (Adst) +  8192 + tid16);   \
    async16(pB0 + (uB), (Bdst)         + tid16);   \
  } while (0)
#define STAGE_PH1(uA, uB, Adst, Bdst)              \
  do {                                             \
    async16(pA2 + (uA), (Adst) + 16384 + tid16);   \
    async16(pA3 + (uA), (Adst) + 24576 + tid16);   \
    async16(pB1 + (uB), (Bdst) +  8192 + tid16);   \
  } while (0)

// One K-tile: 2 phases x {ds_read, stage-issue, barrier, lgkmcnt(0), 16 MFMA, barrier}.
// u = K-tile index being STAGED (t+2); compute buffers passed explicitly.
#define KTILE(u, Ab, Bb, Asd, Bsd, DOSTAGE, LASTWAIT)                       \
  do {                                                                      \
    int uA = 0, uB = 0;                                                     \
    if (DOSTAGE) { int su = (u) >> 2, ku = ((u) & 3) * 64;                  \
                   uA = gcol[su] + ku; uB = wbase[su] + ku; }               \
    ld_frags(Ab, Bb, rA, rB, c0, c1, 0, true, af, bfr);                     \
    if (DOSTAGE) STAGE_PH0(uA, uB, Asd, Bsd);                               \
    __builtin_amdgcn_s_barrier();                                           \
    asm volatile("s_waitcnt lgkmcnt(0)" ::: "memory");                      \
    __builtin_amdgcn_sched_barrier(0);                                      \
    __builtin_amdgcn_s_setprio(1);                                          \
    mma_frags(0, af, bfr, acc);                                             \
    __builtin_amdgcn_s_setprio(0);                                          \
    __builtin_amdgcn_s_barrier();                                           \
    ld_frags(Ab, Bb, rA, rB, c0, c1, 8192, false, af, bfr);                 \
    if (DOSTAGE) STAGE_PH1(uA, uB, Asd, Bsd);                               \
    __builtin_amdgcn_s_barrier();                                           \
    asm volatile("s_waitcnt lgkmcnt(0)" ::: "memory");                      \
    __builtin_amdgcn_sched_barrier(0);                                      \
    __builtin_amdgcn_s_setprio(1);                                          \
    mma_frags(4, af, bfr, acc);                                             \
    __builtin_amdgcn_s_setprio(0);                                          \
    if (DOSTAGE)       { asm volatile("s_waitcnt vmcnt(6)" ::: "memory");   \
                         __builtin_amdgcn_sched_barrier(0); }               \
    else if (LASTWAIT) { asm volatile("s_waitcnt vmcnt(0)" ::: "memory");   \
                         __builtin_amdgcn_sched_barrier(0); }               \
    __builtin_amdgcn_s_barrier();                                           \
  } while (0)

__global__ __launch_bounds__(512, 2)
void bfly_gemm(const unsigned short* __restrict__ xb,   // [8192][4096] bf16
               const unsigned short* __restrict__ wt,   // [80][256 o][256 k] bf16
               const int* __restrict__ fidx,            // [16][5]
               float* __restrict__ out)                 // [8192][4096] fp32
{
  extern __shared__ __align__(16) char smem[];
  char* const b0A = smem;
  char* const b0B = b0A + ABYTES;
  char* const b1A = smem + BUFBYTES;
  char* const b1B = b1A + ABYTES;
  char* const b2A = smem + 2 * BUFBYTES;
  char* const b2B = b2A + ABYTES;

  const int tid = threadIdx.x;
  // 1024 blocks; bijective XCD swizzle (1024 % 8 == 0): each XCD gets 128
  // contiguous logical ids, decoded [ob 16][mt 32][nh 2] -> XCD covers 2 obs
  // (its 10 wt blocks = 1.3 MB stay L2-hot; nh-adjacent ids share A rows).
  const int bx  = blockIdx.x;
  const int swz = (bx & 7) * 128 + (bx >> 3);
  const int ob  = swz >> 6;
  const int mt  = (swz >> 1) & 31;
  const int nh  = swz & 1;
  const int m0  = mt * BM;
  const int n0g = ob * 256 + nh * 128;

  int wbase[ABPI], gcol[ABPI];
  #pragma unroll
  for (int s = 0; s < ABPI; ++s) {
    int fi = __builtin_amdgcn_readfirstlane(fidx[ob * ABPI + s]);  // fi = g*5 + a (uniform)
    wbase[s] = fi * (BS * BS);
    gcol[s]  = (fi / ABPI) * BS;       // g*256: column base in x
  }

  // staging constants: issue covers 64 rows x 8 chunks; logical chunk lc staged
  // at physical slot sc with lc = sc ^ (row&7) (proven 0-conflict swizzle)
  const int sr = tid >> 3;
  const int sc = tid & 7;
  const int lc = sc ^ (sr & 7);
  const int tid16 = tid * 16;
  const unsigned short* pA0 = xb + (size_t)(m0 +   0 + sr) * IN_F + lc * 8;
  const unsigned short* pA1 = xb + (size_t)(m0 +  64 + sr) * IN_F + lc * 8;
  const unsigned short* pA2 = xb + (size_t)(m0 + 128 + sr) * IN_F + lc * 8;
  const unsigned short* pA3 = xb + (size_t)(m0 + 192 + sr) * IN_F + lc * 8;
  const unsigned short* pB0 = wt + (nh * 128 +  0 + sr) * BS + lc * 8;
  const unsigned short* pB1 = wt + (nh * 128 + 64 + sr) * BS + lc * 8;

  // fragment-read constants: 8 waves, 2M x 4N; per-wave 128x32 output
  const int lane = tid & 63;
  const int wv   = tid >> 6;
  const int wm   = (wv >> 2) * 128;
  const int wn   = (wv & 3) * 32;
  const int lrow = lane & 15;          // m (A) / n (B) within 16-tile
  const int quad = lane >> 4;          // k-group
  const int rA = (wm + lrow) * 128;
  const int rB = (wn + lrow) * 128;
  const int c0 = ((quad)     ^ (lrow & 7)) * 16;   // physical chunk for logical ks=0
  const int c1 = ((quad + 4) ^ (lrow & 7)) * 16;   // ks=1

  short8 af[4][2], bfr[2][2];
  floatx4 acc[8][2] = {};

  // ---- prologue: stage K-tiles 0 (buf0) and 1 (buf1); force tile0 complete ----
  {
    const int uA0 = gcol[0], uB0 = wbase[0];
    STAGE_PH0(uA0, uB0, b0A, b0B);
    STAGE_PH1(uA0, uB0, b0A, b0B);
    __builtin_amdgcn_sched_barrier(0);          // keep tile0's 6 issues oldest
    STAGE_PH0(uA0 + 64, uB0 + 64, b1A, b1B);
    STAGE_PH1(uA0 + 64, uB0 + 64, b1A, b1B);
    asm volatile("s_waitcnt vmcnt(6)" ::: "memory");   // tile0 done, tile1 in flight
    __builtin_amdgcn_sched_barrier(0);
    __builtin_amdgcn_s_barrier();
  }

  // ---- main loop: 18 K-tiles; each computes buf t%3 and stages tile t+2 ----
  #pragma unroll 1
  for (int j = 0; j < 6; ++j) {
    const int t = j * 3;
    KTILE(t + 2, b0A, b0B, b2A, b2B, true, false);   // compute t,   stage t+2 -> buf2
    KTILE(t + 3, b1A, b1B, b0A, b0B, true, false);   // compute t+1, stage t+3 -> buf0
    KTILE(t + 4, b2A, b2B, b1A, b1B, true, false);   // compute t+2, stage t+4 -> buf1
  }
  // ---- tail: t=18 (drain tile19's loads), t=19 (no stage, no wait) ----
  KTILE(0, b0A, b0B, b0A, b0B, false, true);
  KTILE(0, b1A, b1B, b0A, b0B, false, false);

  // ---- epilogue: C/D layout col=lane&15, row=quad*4+reg (m89-verified) ----
  #pragma unroll
  for (int m = 0; m < 8; ++m) {
    const int row = m0 + wm + m * 16 + quad * 4;
    #pragma unroll
    for (int n = 0; n < 2; ++n) {
      const int col = n0g + wn + n * 16 + lrow;
      float* po = out + (size_t)row * OUT_F + col;
      #pragma unroll
      for (int r = 0; r < 4; ++r)
        po[(size_t)r * OUT_F] = acc[m][n][r];
    }
  }
}

extern "C" void kernel_launch(void* const* d_in, const int* in_sizes, int n_in,
                              void* d_out, int out_size, void* d_ws, size_t ws_size,
                              hipStream_t stream) {
  const float* x  = (const float*)d_in[0];          // [8192][4096]
  const float* w  = (const float*)d_in[1];          // [4096][5][256]
  const int* fidx = (const int*)d_in[2];            // [16][5]
  float* out = (float*)d_out;

  // workspace: xb (64 MiB bf16) then wt (10 MiB bf16) = 74 MiB total
  unsigned short* xb = (unsigned short*)d_ws;
  unsigned short* wt = xb + (size_t)N_TOK * IN_F;

  static int smem_set = 0;
  if (!smem_set) {
    hipFuncSetAttribute((const void*)bfly_gemm,
                        hipFuncAttributeMaxDynamicSharedMemorySize, SMEM_TOTAL);
    smem_set = 1;
  }

  cvt_x_kernel<<<(N_TOK * IN_F) / (8 * 256), 256, 0, stream>>>((const float4*)x, (ushort8v*)xb);
  cvt_w_kernel<<<NFLAT * 16, 256, 0, stream>>>(w, wt);
  bfly_gemm<<<16 * 32 * 2, 512, SMEM_TOTAL, stream>>>(xb, wt, fidx, out);
}

// Round 4
// 323.631 us; speedup vs baseline: 1.0989x; 1.0297x over previous
//
#include <hip/hip_runtime.h>
#include <stdint.h>

// Problem constants (fixed by the reference)
#define N_TOK 8192
#define IN_F 4096
#define OUT_F 4096
#define BS 256
#define ABPI 5
#define NFLAT 80          // 16 output blocks x 5 slots = all (g,a) pairs

typedef __attribute__((ext_vector_type(8))) short short8;    // 8 bf16 = 4 VGPRs (MFMA A/B frag)
typedef __attribute__((ext_vector_type(4))) float floatx4;   // MFMA C/D frag
typedef __attribute__((ext_vector_type(4))) unsigned short ushort4v;
typedef __attribute__((ext_vector_type(8))) unsigned short ushort8v;

__device__ __forceinline__ unsigned short f2bf(float f) {
  union { float f; unsigned int u; } v; v.f = f;
  unsigned int r = v.u + 0x7FFFu + ((v.u >> 16) & 1u);   // RNE
  return (unsigned short)(r >> 16);
}

__device__ __forceinline__ void async16(const void* g, void* l) {
  __builtin_amdgcn_global_load_lds((const __attribute__((address_space(1))) void*)g,
                                   (__attribute__((address_space(3))) void*)l, 16, 0, 0);
}

// ---------------- kernel 1: x fp32 -> bf16 ----------------
__global__ void cvt_x_kernel(const float4* __restrict__ x, ushort8v* __restrict__ xb) {
  int idx = blockIdx.x * 256 + threadIdx.x;
  float4 a = x[idx * 2], b = x[idx * 2 + 1];
  ushort8v o;
  o[0] = f2bf(a.x); o[1] = f2bf(a.y); o[2] = f2bf(a.z); o[3] = f2bf(a.w);
  o[4] = f2bf(b.x); o[5] = f2bf(b.y); o[6] = f2bf(b.z); o[7] = f2bf(b.w);
  xb[idx] = o;
}

// ---------------- kernel 2: weight fp32 -> bf16, transposed per (g,a) block ----
__global__ void cvt_w_kernel(const float* __restrict__ w, unsigned short* __restrict__ wt) {
  __shared__ unsigned short tile[64][68];
  int b = blockIdx.x;
  int fi = b >> 4;
  int t  = b & 15;
  int k0 = (t >> 2) * 64, o0 = (t & 3) * 64;
  int g = fi / ABPI, a = fi % ABPI;
  int tid = threadIdx.x;
  int tr = tid >> 4, tc = tid & 15;
  #pragma unroll
  for (int i = 0; i < 4; ++i) {
    int k = k0 + i * 16 + tr;
    const float* src = w + (size_t)(g * 256 + k) * (ABPI * BS) + a * BS + o0 + tc * 4;
    float4 v = *(const float4*)src;
    tile[tc * 4 + 0][i * 16 + tr] = f2bf(v.x);
    tile[tc * 4 + 1][i * 16 + tr] = f2bf(v.y);
    tile[tc * 4 + 2][i * 16 + tr] = f2bf(v.z);
    tile[tc * 4 + 3][i * 16 + tr] = f2bf(v.w);
  }
  __syncthreads();
  #pragma unroll
  for (int i = 0; i < 4; ++i) {
    int o = i * 16 + tr;
    unsigned short* dst = wt + (size_t)fi * (BS * BS) + (size_t)(o0 + o) * BS + k0 + tc * 4;
    *(ushort4v*)dst = *(const ushort4v*)&tile[o][tc * 4];
  }
}

// ---------------- kernel 3: butterfly block-sparse GEMM ------------------------
// 256x256 tile, 8 waves (2M x 4N), per-wave 128x64 output, BK=64, DOUBLE-buffered
// LDS (2 x 64 KiB). 4-phase quadrant walk per K-tile with register reuse:
//   P1 (m0,n01): read A-half0 (8 b128) + B tiles 0,1 (4)   | stage t+1: A{0,2},B{0,1}
//   P2 (m0,n23): read B tiles 2,3 (4)                      | stage t+1: B{2,3}
//   P3 (m1,n23): read A-half1 (8)                          | stage t+1: A{1,3}
//   P4 (m1,n01): no reads (all regs live)
// Counted waits (never 0 in loop). Per-KTILE a wave issues 8 loads (4+2+2).
// Invariant: enter KTILE(t) with 2 outstanding (A1,A3 of t). P1->6, P2->8;
// vmcnt(6) at P2-end drains exactly A1,A3 of t (before P3 reads them); P3->8;
// vmcnt(2) at P4-end drains the 6 tile-t+1 loads A0,A2,B0-B3, leaving A1,A3 of
// t+1. Each wait is followed by s_barrier so all waves' stores are LDS-visible.
// Buffer c^1 holds tile t-1 whose ds_reads were lgkmcnt(0)-drained >=2 barriers
// before any t+1 stage issue (write-after-read safe).

#define BM 256
#define BN 256
#define BK 64
#define ABYTES 32768              // 256 rows x 128 B
#define BUFBYTES 65536            // A + B
#define SMEM_TOTAL 131072         // 2 buffers

__device__ __forceinline__ void ld_half_A(const char* p, int c0, int c1, short8 (&af)[4][2]) {
  #pragma unroll
  for (int mt = 0; mt < 4; ++mt) {
    const char* q = p + mt * 2048;
    af[mt][0] = *(const short8*)(q + c0);
    af[mt][1] = *(const short8*)(q + c1);
  }
}

__device__ __forceinline__ void ld_pair_B(const char* p, int c0, int c1, short8 (&bf)[2][2]) {
  #pragma unroll
  for (int nt = 0; nt < 2; ++nt) {
    const char* q = p + nt * 2048;
    bf[nt][0] = *(const short8*)(q + c0);
    bf[nt][1] = *(const short8*)(q + c1);
  }
}

__device__ __forceinline__ void mma16(const short8 (&af)[4][2], const short8 (&bf)[2][2],
                                      floatx4 (&acc)[8][4], int mb, int nb) {
  #pragma unroll
  for (int mt = 0; mt < 4; ++mt)
    #pragma unroll
    for (int nt = 0; nt < 2; ++nt) {
      acc[mb + mt][nb + nt] =
          __builtin_amdgcn_mfma_f32_16x16x32_bf16(af[mt][0], bf[nt][0], acc[mb + mt][nb + nt], 0, 0, 0);
      acc[mb + mt][nb + nt] =
          __builtin_amdgcn_mfma_f32_16x16x32_bf16(af[mt][1], bf[nt][1], acc[mb + mt][nb + nt], 0, 0, 0);
    }
}

#define PH_OPEN                                            \
  __builtin_amdgcn_s_barrier();                            \
  asm volatile("s_waitcnt lgkmcnt(0)" ::: "memory");       \
  __builtin_amdgcn_sched_barrier(0);                       \
  __builtin_amdgcn_s_setprio(1)

#define KTILE(tt, Ab, Bb, Asd, Bsd, DOSTAGE, LAST)                              \
  do {                                                                          \
    int uA = 0, uB = 0;                                                         \
    if (DOSTAGE) { const int u = (tt) + 1, su = u >> 2, ku = (u & 3) * 64;      \
                   uA = gcol[su] + ku; uB = wbase[su] + ku; }                   \
    /* P1: (m-half0, n-tiles 0,1) */                                            \
    ld_half_A((Ab) + rAb, c0, c1, af);                                          \
    ld_pair_B((Bb) + rBb, c0, c1, bf01);                                        \
    if (DOSTAGE) { async16(pA0 + uA, (Asd)         + tid16);                    \
                   async16(pA2 + uA, (Asd) + 16384 + tid16);                    \
                   async16(pB0 + uB, (Bsd)         + tid16);                    \
                   async16(pB1 + uB, (Bsd) +  8192 + tid16); }                  \
    PH_OPEN; mma16(af, bf01, acc, 0, 0);                                        \
    __builtin_amdgcn_s_setprio(0);                                              \
    __builtin_amdgcn_s_barrier();                                               \
    /* P2: (m-half0, n-tiles 2,3) */                                            \
    ld_pair_B((Bb) + rBb + 4096, c0, c1, bf23);                                 \
    if (DOSTAGE) { async16(pB2 + uB, (Bsd) + 16384 + tid16);                    \
                   async16(pB3 + uB, (Bsd) + 24576 + tid16); }                  \
    PH_OPEN; mma16(af, bf23, acc, 0, 2);                                        \
    __builtin_amdgcn_s_setprio(0);                                              \
    if (DOSTAGE)   { asm volatile("s_waitcnt vmcnt(6)" ::: "memory");           \
                     __builtin_amdgcn_sched_barrier(0); }                       \
    else if (LAST) { asm volatile("s_waitcnt vmcnt(0)" ::: "memory");           \
                     __builtin_amdgcn_sched_barrier(0); }                       \
    __builtin_amdgcn_s_barrier();                                               \
    /* P3: (m-half1, n-tiles 2,3) */                                            \
    ld_half_A((Ab) + rAb + 8192, c0, c1, af);                                   \
    if (DOSTAGE) { async16(pA1 + uA, (Asd) +  8192 + tid16);                    \
                   async16(pA3 + uA, (Asd) + 24576 + tid16); }                  \
    PH_OPEN; mma16(af, bf23, acc, 4, 2);                                        \
    __builtin_amdgcn_s_setprio(0);                                              \
    __builtin_amdgcn_s_barrier();                                               \
    /* P4: (m-half1, n-tiles 0,1) — pure register reuse */                      \
    __builtin_amdgcn_s_setprio(1);                                              \
    mma16(af, bf01, acc, 4, 0);                                                 \
    __builtin_amdgcn_s_setprio(0);                                              \
    if (DOSTAGE) { asm volatile("s_waitcnt vmcnt(2)" ::: "memory");             \
                   __builtin_amdgcn_sched_barrier(0); }                         \
    __builtin_amdgcn_s_barrier();                                               \
  } while (0)

__global__ __launch_bounds__(512, 2)
void bfly_gemm(const unsigned short* __restrict__ xb,   // [8192][4096] bf16
               const unsigned short* __restrict__ wt,   // [80][256 o][256 k] bf16
               const int* __restrict__ fidx,            // [16][5]
               float* __restrict__ out)                 // [8192][4096] fp32
{
  extern __shared__ __align__(16) char smem[];
  char* const b0A = smem;
  char* const b0B = b0A + ABYTES;
  char* const b1A = smem + BUFBYTES;
  char* const b1B = b1A + ABYTES;

  const int tid = threadIdx.x;
  // 512 blocks; bijective XCD swizzle (512 % 8 == 0): each XCD gets 64
  // contiguous logical ids = 2 full output-block-columns (its 10 wt blocks
  // = 1.25 MiB stay L2-hot across all 32 m-tiles).
  const int bx  = blockIdx.x;
  const int swz = (bx & 7) * 64 + (bx >> 3);
  const int ob  = swz >> 5;            // 0..15
  const int mt0 = swz & 31;            // 0..31
  const int m0  = mt0 * BM;
  const int n0g = ob * 256;

  int wbase[ABPI], gcol[ABPI];
  #pragma unroll
  for (int s = 0; s < ABPI; ++s) {
    int fi = __builtin_amdgcn_readfirstlane(fidx[ob * ABPI + s]);  // fi = g*5 + a
    wbase[s] = fi * (BS * BS);
    gcol[s]  = (fi / ABPI) * BS;
  }

  // staging constants: each issue covers 64 rows x 8 chunks of 16 B; logical
  // k-chunk lc staged at physical slot sc with lc = sc ^ (row&7) (0-conflict)
  const int sr = tid >> 3;
  const int sc = tid & 7;
  const int lc = sc ^ (sr & 7);
  const int tid16 = tid * 16;
  const unsigned short* pA0 = xb + (size_t)(m0 +   0 + sr) * IN_F + lc * 8;
  const unsigned short* pA1 = xb + (size_t)(m0 +  64 + sr) * IN_F + lc * 8;
  const unsigned short* pA2 = xb + (size_t)(m0 + 128 + sr) * IN_F + lc * 8;
  const unsigned short* pA3 = xb + (size_t)(m0 + 192 + sr) * IN_F + lc * 8;
  const unsigned short* pB0 = wt + (  0 + sr) * BS + lc * 8;
  const unsigned short* pB1 = wt + ( 64 + sr) * BS + lc * 8;
  const unsigned short* pB2 = wt + (128 + sr) * BS + lc * 8;
  const unsigned short* pB3 = wt + (192 + sr) * BS + lc * 8;

  // fragment-read constants: 8 waves 2M x 4N; per-wave 128 m x 64 n
  const int lane = tid & 63;
  const int wv   = tid >> 6;
  const int wm   = (wv >> 2) * 128;    // 0 or 128
  const int wn   = (wv & 3) * 64;      // 0,64,128,192
  const int lrow = lane & 15;
  const int quad = lane >> 4;
  const int rAb  = (wm + lrow) * 128;  // byte; A row stride 128 B
  const int rBb  = (wn + lrow) * 128;
  const int c0   = ((quad)     ^ (lrow & 7)) * 16;
  const int c1   = ((quad + 4) ^ (lrow & 7)) * 16;

  short8 af[4][2], bf01[2][2], bf23[2][2];
  floatx4 acc[8][4] = {};

  // ---- prologue: stage K-tile 0 fully into buf0, drain once ----
  {
    const int uA0 = gcol[0], uB0 = wbase[0];
    async16(pA0 + uA0, b0A         + tid16);
    async16(pA1 + uA0, b0A +  8192 + tid16);
    async16(pA2 + uA0, b0A + 16384 + tid16);
    async16(pA3 + uA0, b0A + 24576 + tid16);
    async16(pB0 + uB0, b0B         + tid16);
    async16(pB1 + uB0, b0B +  8192 + tid16);
    async16(pB2 + uB0, b0B + 16384 + tid16);
    async16(pB3 + uB0, b0B + 24576 + tid16);
    asm volatile("s_waitcnt vmcnt(0)" ::: "memory");
    __builtin_amdgcn_sched_barrier(0);
    __builtin_amdgcn_s_barrier();
  }

  // ---- main loop: K = 1280 = 20 K-tiles; tile t computes buf t&1, stages t+1 ----
  #pragma unroll 1
  for (int j = 0; j < 9; ++j) {
    const int t = j * 2;
    KTILE(t,     b0A, b0B, b1A, b1B, true, false);
    KTILE(t + 1, b1A, b1B, b0A, b0B, true, false);
  }
  KTILE(18, b0A, b0B, b1A, b1B, true, false);
  KTILE(19, b1A, b1B, b0A, b0B, false, true);

  // ---- epilogue: C/D layout col=lane&15, row=quad*4+reg (m89-verified) ----
  #pragma unroll
  for (int m = 0; m < 8; ++m) {
    const int row = m0 + wm + (m >> 2) * 64 + (m & 3) * 16 + quad * 4;
    #pragma unroll
    for (int n = 0; n < 4; ++n) {
      const int col = n0g + wn + n * 16 + lrow;
      float* po = out + (size_t)row * OUT_F + col;
      #pragma unroll
      for (int r = 0; r < 4; ++r)
        po[(size_t)r * OUT_F] = acc[m][n][r];
    }
  }
}

extern "C" void kernel_launch(void* const* d_in, const int* in_sizes, int n_in,
                              void* d_out, int out_size, void* d_ws, size_t ws_size,
                              hipStream_t stream) {
  const float* x  = (const float*)d_in[0];          // [8192][4096]
  const float* w  = (const float*)d_in[1];          // [4096][5][256]
  const int* fidx = (const int*)d_in[2];            // [16][5]
  float* out = (float*)d_out;

  unsigned short* xb = (unsigned short*)d_ws;
  unsigned short* wt = xb + (size_t)N_TOK * IN_F;

  static int smem_set = 0;
  if (!smem_set) {
    hipFuncSetAttribute((const void*)bfly_gemm,
                        hipFuncAttributeMaxDynamicSharedMemorySize, SMEM_TOTAL);
    smem_set = 1;
  }

  cvt_x_kernel<<<(N_TOK * IN_F) / (8 * 256), 256, 0, stream>>>((const float4*)x, (ushort8v*)xb);
  cvt_w_kernel<<<NFLAT * 16, 256, 0, stream>>>(w, wt);
  bfly_gemm<<<16 * 32, 512, SMEM_TOTAL, stream>>>(xb, wt, fidx, out);
}